// Round 21
// baseline (97.058 us; speedup 1.0000x reference)
//
#include <hip/hip_runtime.h>

#define DI __device__ __forceinline__

using f32x4  = __attribute__((ext_vector_type(4))) float;
using bf16x8 = __attribute__((ext_vector_type(8))) short;
using u32x4  = __attribute__((ext_vector_type(4))) unsigned int;

DI unsigned short f2bf(float f) {
    unsigned int u = __float_as_uint(f);
    unsigned int r = u + 0x7FFFu + ((u >> 16) & 1u);
    return (unsigned short)(r >> 16);
}

// async global->LDS, 16B per lane (wave-uniform LDS base + lane*16)
DI void gload_lds16(const void* g, void* l) {
    __builtin_amdgcn_global_load_lds(
        (const __attribute__((address_space(1))) void*)(unsigned long long)g,
        (__attribute__((address_space(3))) void*)(unsigned int)(unsigned long long)l,
        16, 0, 0);
}

// ---- problem constants ----
constexpr int N_SEQ = 8192;
constexpr int QH    = 32;
constexpr int KH    = 2;
constexpr int D     = 128;
constexpr int M_CMP = 511;
constexpr int MP    = 512;
constexpr int NCH   = 16;                       // 512/32 chunks
constexpr int CHUNK_ELEMS = 16 * 64 * 8;        // 16 frags x 64 lanes x 8 = 16KB
constexpr int HSTRIDE = NCH * CHUNK_ELEMS;      // per-head elems

// ============ Stage 1: block compress (verified) ============
// Unified fragment-major KV: kvb[h][c][fi][lane][8], fi 0-7 = ck frags
// (fi = mt*4+kc), fi 8-15 = cv frags (fi = 8+dt). One chunk = contiguous 16KB.
// cv k-slot mapping (shared with in-register P): k = hi*8+e -> m = (e>>2)*16+hi*4+(e&3).
__global__ __launch_bounds__(256)
void compress_kernel(const float* __restrict__ kin, const float* __restrict__ vin,
                     const float* __restrict__ w_key, const float* __restrict__ pe_key,
                     const float* __restrict__ w_val, const float* __restrict__ pe_val,
                     float* __restrict__ ck_out,
                     unsigned short* __restrict__ kvb)
{
    const int m  = blockIdx.x;      // 0..511 (511 = zero pad)
    const int t  = threadIdx.x;
    const int hh = t >> 7;
    const int d  = t & 127;
    float acck = 0.f, accv = 0.f;
    if (m < M_CMP) {
        #pragma unroll
        for (int k = 0; k < 32; ++k) {
            float xk = kin[((m*16 + k)*KH + hh)*D + d];
            float xv = vin[((m*16 + k)*KH + hh)*D + d];
            acck += (xk + pe_key[k*D + d]) * w_key[k];
            accv += (xv + pe_val[k*D + d]) * w_val[k];
        }
        acck *= (1.f/32.f);
        accv *= (1.f/32.f);
        ck_out[(m*KH + hh)*D + d] = acck;
    }
    const int c = m >> 5, ml = m & 31;
    {
        const int mt = ml >> 4, colx = ml & 15;
        const int kc = d >> 5, hix = (d >> 3) & 3, e = d & 7;
        kvb[(size_t)hh*HSTRIDE + (((c*16 + mt*4 + kc)*64) + hix*16 + colx)*8 + e] = f2bf(acck);
    }
    {
        const int e   = ((ml >> 4) << 2) + (ml & 3);
        const int hix = (ml >> 2) & 3;
        const int dt  = d >> 4, colx = d & 15;
        kvb[(size_t)hh*HSTRIDE + (((c*16 + 8 + dt)*64) + hix*16 + colx)*8 + e] = f2bf(accv);
    }
}

// ============ Stage 2: best-measured schedule (R16, 93.59 us scored) ========
// 256 threads = 4 waves; wave owns consecutive rows n0 = bx*8+wid*2 and n0+1.
// Heavy-first dispatch. 3-buffer counted-vmcnt(4) pipeline, ONE barrier/iter,
// no vmcnt(0) drain in loop. Branch-free dual-row MFMA (masked rows add 0).
// PV = one 16x16x32 MFMA per dt per row, in-place inline asm. T5 setprio.
__global__ __launch_bounds__(256)
void attn_kernel(const float* __restrict__ q,
                 const unsigned short* __restrict__ kvb,
                 float* __restrict__ o,
                 float* __restrict__ lse)
{
    __shared__ __align__(16) unsigned short lds[3][16][64][8];   // 3 x 16KB

    const int h    = blockIdx.y;
    const int bx   = (N_SEQ/8 - 1) - blockIdx.x;   // heavy-first
    const int t    = threadIdx.x;
    const int wid  = t >> 6;          // 0..3
    const int lane = t & 63;
    const int col  = lane & 15;
    const int hi   = lane >> 4;

    const int n0r = (bx << 3) + (wid << 1);        // even row
    const int n1r = n0r + 1;                       // odd row
    const int mcnt0 = (n0r >= 31) ? (((n0r - 31) >> 4) + 1) : 0;
    const int mcnt1 = (n1r >= 31) ? (((n1r - 31) >> 4) + 1) : 0;
    const int nmax  = (bx << 3) + 7;
    const int nchb  = (nmax >= 31) ? (((((nmax - 31) >> 4) + 1) + 31) >> 5) : 0;

    const float sm_scale = 0.08838834764831845f;
    const float NEG_INF  = -__builtin_inff();

    // ---- Q fragments (B-frag of swapped QK^T): B[k=d][col=g] ----
    bf16x8 qf0[4], qf1[4];
    {
        const float* qp0 = q + ((size_t)n0r*QH + (h << 4) + col)*D + (hi << 3);
        const float* qp1 = q + ((size_t)n1r*QH + (h << 4) + col)*D + (hi << 3);
        #pragma unroll
        for (int kc = 0; kc < 4; ++kc) {
            f32x4 a0 = *(const f32x4*)(qp0 + kc*32);
            f32x4 b0 = *(const f32x4*)(qp0 + kc*32 + 4);
            f32x4 a1 = *(const f32x4*)(qp1 + kc*32);
            f32x4 b1 = *(const f32x4*)(qp1 + kc*32 + 4);
            bf16x8 f0, f1;
            f0[0]=(short)f2bf(a0[0]*sm_scale); f0[1]=(short)f2bf(a0[1]*sm_scale);
            f0[2]=(short)f2bf(a0[2]*sm_scale); f0[3]=(short)f2bf(a0[3]*sm_scale);
            f0[4]=(short)f2bf(b0[0]*sm_scale); f0[5]=(short)f2bf(b0[1]*sm_scale);
            f0[6]=(short)f2bf(b0[2]*sm_scale); f0[7]=(short)f2bf(b0[3]*sm_scale);
            f1[0]=(short)f2bf(a1[0]*sm_scale); f1[1]=(short)f2bf(a1[1]*sm_scale);
            f1[2]=(short)f2bf(a1[2]*sm_scale); f1[3]=(short)f2bf(a1[3]*sm_scale);
            f1[4]=(short)f2bf(b1[0]*sm_scale); f1[5]=(short)f2bf(b1[1]*sm_scale);
            f1[6]=(short)f2bf(b1[2]*sm_scale); f1[7]=(short)f2bf(b1[3]*sm_scale);
            qf0[kc] = f0; qf1[kc] = f1;
        }
    }

    f32x4 oacc0[8], oacc1[8];
    #pragma unroll
    for (int dt = 0; dt < 8; ++dt) {
        oacc0[dt] = (f32x4){0.f,0.f,0.f,0.f};
        oacc1[dt] = (f32x4){0.f,0.f,0.f,0.f};
    }
    float rmax0 = -3e38f, rmax1 = -3e38f, rsum0 = 0.f, rsum1 = 0.f;

    const unsigned short* kvh = kvb + (size_t)h*HSTRIDE;

    auto STAGE = [&](int buf, int c) {
        const unsigned short* gp = kvh + ((size_t)(c*16 + (wid << 2))*64 + lane)*8;
        #pragma unroll
        for (int p = 0; p < 4; ++p)
            gload_lds16(gp + p*512, &lds[buf][(wid << 2) + p][lane][0]);
    };

    // softmax -> 4 packed bf16 words (B-frag of 16x16x32 PV)
    auto SMAX = [&](f32x4 sa, f32x4 sb, int lim, float& rm, float& rs,
                    f32x4* oaccr, unsigned int* pw) {
        float sv[8];
        if (lim < 32) {                      // boundary / inactive chunks
            const int mb = hi << 2;
            #pragma unroll
            for (int jj = 0; jj < 4; ++jj) {
                sv[jj]     = (mb + jj      < lim) ? sa[jj] : NEG_INF;
                sv[4 + jj] = (mb + jj + 16 < lim) ? sb[jj] : NEG_INF;
            }
        } else {
            #pragma unroll
            for (int jj = 0; jj < 4; ++jj) { sv[jj] = sa[jj]; sv[4 + jj] = sb[jj]; }
        }
        float pm = fmaxf(fmaxf(fmaxf(sv[0],sv[1]), fmaxf(sv[2],sv[3])),
                         fmaxf(fmaxf(sv[4],sv[5]), fmaxf(sv[6],sv[7])));
        if (!__all(pm <= rm + 8.0f)) {
            float tm = pm;
            tm = fmaxf(tm, __shfl_xor(tm, 16));
            tm = fmaxf(tm, __shfl_xor(tm, 32));
            float nm = fmaxf(rm, tm);
            float sc = __expf(rm - nm);
            rs *= sc;
            #pragma unroll
            for (int dt = 0; dt < 8; ++dt) {
                oaccr[dt][0] *= sc; oaccr[dt][1] *= sc;
                oaccr[dt][2] *= sc; oaccr[dt][3] *= sc;
            }
            rm = nm;
        }
        float p[8];
        #pragma unroll
        for (int i = 0; i < 8; ++i) p[i] = __expf(sv[i] - rm);
        rs += ((p[0]+p[1]) + (p[2]+p[3])) + ((p[4]+p[5]) + (p[6]+p[7]));
        asm("v_cvt_pk_bf16_f32 %0, %1, %2" : "=v"(pw[0]) : "v"(p[0]), "v"(p[1]));
        asm("v_cvt_pk_bf16_f32 %0, %1, %2" : "=v"(pw[1]) : "v"(p[2]), "v"(p[3]));
        asm("v_cvt_pk_bf16_f32 %0, %1, %2" : "=v"(pw[2]) : "v"(p[4]), "v"(p[5]));
        asm("v_cvt_pk_bf16_f32 %0, %1, %2" : "=v"(pw[3]) : "v"(p[6]), "v"(p[7]));
    };

    if (nchb > 0) {
        // ---- prologue: stage chunks 0 and 1 (clamped for tiny blocks) ----
        STAGE(0, 0);
        STAGE(1, (1 < nchb) ? 1 : 0);

        for (int c = 0; c < nchb; ++c) {
            asm volatile("s_waitcnt vmcnt(4)" ::: "memory");
            __builtin_amdgcn_s_barrier();
            __builtin_amdgcn_sched_barrier(0);

            const int cn = (c + 2 < nchb) ? (c + 2) : (nchb - 1);
            STAGE((c + 2) % 3, cn);

            const int m0 = c << 5;
            const unsigned short (*L)[64][8] = lds[c % 3];

            // ---- QK^T: 16 straight-line MFMAs, both rows ----
            f32x4 s10 = (f32x4){0,0,0,0}, s11 = (f32x4){0,0,0,0};
            f32x4 s00 = (f32x4){0,0,0,0}, s01 = (f32x4){0,0,0,0};
            __builtin_amdgcn_s_setprio(1);
            #pragma unroll
            for (int kc = 0; kc < 4; ++kc) {
                bf16x8 ca = *(const bf16x8*)&L[kc][lane][0];
                bf16x8 cb = *(const bf16x8*)&L[4 + kc][lane][0];
                s10 = __builtin_amdgcn_mfma_f32_16x16x32_bf16(ca, qf1[kc], s10, 0, 0, 0);
                s11 = __builtin_amdgcn_mfma_f32_16x16x32_bf16(cb, qf1[kc], s11, 0, 0, 0);
                s00 = __builtin_amdgcn_mfma_f32_16x16x32_bf16(ca, qf0[kc], s00, 0, 0, 0);
                s01 = __builtin_amdgcn_mfma_f32_16x16x32_bf16(cb, qf0[kc], s01, 0, 0, 0);
            }
            __builtin_amdgcn_s_setprio(0);

            unsigned int pw1[4], pw0[4];
            SMAX(s10, s11, mcnt1 - m0, rmax1, rsum1, oacc1, pw1);
            SMAX(s00, s01, mcnt0 - m0, rmax0, rsum0, oacc0, pw0);

            // ---- PV: one 16x16x32 MFMA per dt per row (in-place asm) ----
            {
                u32x4 b1v = {pw1[0], pw1[1], pw1[2], pw1[3]};
                u32x4 b0v = {pw0[0], pw0[1], pw0[2], pw0[3]};
                __builtin_amdgcn_s_setprio(1);
                #pragma unroll
                for (int dt = 0; dt < 8; ++dt) {
                    bf16x8 cv = *(const bf16x8*)&L[8 + dt][lane][0];
                    asm("v_mfma_f32_16x16x32_bf16 %0, %1, %2, %0"
                        : "+v"(oacc1[dt]) : "v"(cv), "v"(b1v));
                    asm("v_mfma_f32_16x16x32_bf16 %0, %1, %2, %0"
                        : "+v"(oacc0[dt]) : "v"(cv), "v"(b0v));
                }
                __builtin_amdgcn_s_setprio(0);
            }
        }
    }

    // ---- epilogue ----
    auto EPI = [&](int n, float rm, float rs, f32x4* oaccr, bool valid) {
        float r = rs;
        r += __shfl_xor(r, 16);
        r += __shfl_xor(r, 32);
        const float inv = valid ? (1.0f / r) : 0.0f;
        float* op = o + ((size_t)n*QH + (h << 4) + col)*D + (hi << 2);
        #pragma unroll
        for (int dt = 0; dt < 8; ++dt) {
            f32x4 w = oaccr[dt];
            w[0] *= inv; w[1] *= inv; w[2] *= inv; w[3] *= inv;
            *(f32x4*)(op + dt*16) = w;
        }
        if (lane < 16) {
            float lv = valid ? (rm + __logf(r)) : 0.0f;
            lse[((size_t)(h << 4) + col)*N_SEQ + n] = lv;
        }
    };
    EPI(n0r, rmax0, rsum0, oacc0, mcnt0 > 0);
    EPI(n1r, rmax1, rsum1, oacc1, mcnt1 > 0);
}

extern "C" void kernel_launch(void* const* d_in, const int* in_sizes, int n_in,
                              void* d_out, int out_size, void* d_ws, size_t ws_size,
                              hipStream_t stream)
{
    const float* q      = (const float*)d_in[0];
    const float* k      = (const float*)d_in[1];
    const float* v      = (const float*)d_in[2];
    const float* w_key  = (const float*)d_in[3];
    const float* pe_key = (const float*)d_in[4];
    const float* w_val  = (const float*)d_in[5];
    const float* pe_val = (const float*)d_in[6];

    float* o   = (float*)d_out;                    // (1, 8192, 32, 128)
    float* lse = o + (size_t)N_SEQ * QH * D;       // (1, 32, 8192)
    float* ck  = lse + (size_t)QH * N_SEQ;         // (1, 511, 2, 128)

    unsigned short* kvb = (unsigned short*)d_ws;   // [KH][NCH][16][64][8] bf16

    compress_kernel<<<dim3(MP), dim3(256), 0, stream>>>(
        k, v, w_key, pe_key, w_val, pe_val, ck, kvb);

    attn_kernel<<<dim3(N_SEQ/8, KH), dim3(256), 0, stream>>>(
        q, kvb, o, lse);
}

// Round 22
// 92.212 us; speedup vs baseline: 1.0526x; 1.0526x over previous
//
#include <hip/hip_runtime.h>

#define DI __device__ __forceinline__

using f32x4  = __attribute__((ext_vector_type(4))) float;
using bf16x8 = __attribute__((ext_vector_type(8))) short;
using u32x4  = __attribute__((ext_vector_type(4))) unsigned int;

DI unsigned short f2bf(float f) {
    unsigned int u = __float_as_uint(f);
    unsigned int r = u + 0x7FFFu + ((u >> 16) & 1u);
    return (unsigned short)(r >> 16);
}

// async global->LDS, 16B per lane (wave-uniform LDS base + lane*16)
DI void gload_lds16(const void* g, void* l) {
    __builtin_amdgcn_global_load_lds(
        (const __attribute__((address_space(1))) void*)(unsigned long long)g,
        (__attribute__((address_space(3))) void*)(unsigned int)(unsigned long long)l,
        16, 0, 0);
}

// ---- problem constants ----
constexpr int N_SEQ = 8192;
constexpr int QH    = 32;
constexpr int KH    = 2;
constexpr int D     = 128;
constexpr int M_CMP = 511;
constexpr int MP    = 512;
constexpr int NCH   = 16;                       // 512/32 chunks
constexpr int CHUNK_ELEMS = 16 * 64 * 8;        // 16 frags x 64 lanes x 8 = 16KB
constexpr int HSTRIDE = NCH * CHUNK_ELEMS;      // per-head elems

// ============ Stage 1: block compress (verified) ============
__global__ __launch_bounds__(256)
void compress_kernel(const float* __restrict__ kin, const float* __restrict__ vin,
                     const float* __restrict__ w_key, const float* __restrict__ pe_key,
                     const float* __restrict__ w_val, const float* __restrict__ pe_val,
                     float* __restrict__ ck_out,
                     unsigned short* __restrict__ kvb)
{
    const int m  = blockIdx.x;      // 0..511 (511 = zero pad)
    const int t  = threadIdx.x;
    const int hh = t >> 7;
    const int d  = t & 127;
    float acck = 0.f, accv = 0.f;
    if (m < M_CMP) {
        #pragma unroll
        for (int k = 0; k < 32; ++k) {
            float xk = kin[((m*16 + k)*KH + hh)*D + d];
            float xv = vin[((m*16 + k)*KH + hh)*D + d];
            acck += (xk + pe_key[k*D + d]) * w_key[k];
            accv += (xv + pe_val[k*D + d]) * w_val[k];
        }
        acck *= (1.f/32.f);
        accv *= (1.f/32.f);
        ck_out[(m*KH + hh)*D + d] = acck;
    }
    const int c = m >> 5, ml = m & 31;
    {
        const int mt = ml >> 4, colx = ml & 15;
        const int kc = d >> 5, hix = (d >> 3) & 3, e = d & 7;
        kvb[(size_t)hh*HSTRIDE + (((c*16 + mt*4 + kc)*64) + hix*16 + colx)*8 + e] = f2bf(acck);
    }
    {
        const int e   = ((ml >> 4) << 2) + (ml & 3);
        const int hix = (ml >> 2) & 3;
        const int dt  = d >> 4, colx = d & 15;
        kvb[(size_t)hh*HSTRIDE + (((c*16 + 8 + dt)*64) + hix*16 + colx)*8 + e] = f2bf(accv);
    }
}

// ============ Stage 2: R16 datapath, 2-buffer 32KB LDS (4 blocks/CU) ========
// 256 threads = 4 waves; wave owns consecutive rows n0 = bx*8+wid*2, n0+1.
// Heavy-first. Per iter: vmcnt(0) on own chunk-c loads (issued one compute
// phase earlier -> ~free) -> ONE barrier -> stage c+1 -> compute. Dropping
// the 3rd buffer cuts LDS 48->32KB: 3->4 resident blocks/CU (+33% waves),
// each block on an independent barrier clock.
__global__ __launch_bounds__(256)
void attn_kernel(const float* __restrict__ q,
                 const unsigned short* __restrict__ kvb,
                 float* __restrict__ o,
                 float* __restrict__ lse)
{
    __shared__ __align__(16) unsigned short lds[2][16][64][8];   // 2 x 16KB

    const int h    = blockIdx.y;
    const int bx   = (N_SEQ/8 - 1) - blockIdx.x;   // heavy-first
    const int t    = threadIdx.x;
    const int wid  = t >> 6;          // 0..3
    const int lane = t & 63;
    const int col  = lane & 15;
    const int hi   = lane >> 4;

    const int n0r = (bx << 3) + (wid << 1);        // even row
    const int n1r = n0r + 1;                       // odd row
    const int mcnt0 = (n0r >= 31) ? (((n0r - 31) >> 4) + 1) : 0;
    const int mcnt1 = (n1r >= 31) ? (((n1r - 31) >> 4) + 1) : 0;
    const int nmax  = (bx << 3) + 7;
    const int nchb  = (nmax >= 31) ? (((((nmax - 31) >> 4) + 1) + 31) >> 5) : 0;

    const float sm_scale = 0.08838834764831845f;
    const float NEG_INF  = -__builtin_inff();

    // ---- Q fragments (B-frag of swapped QK^T): B[k=d][col=g] ----
    bf16x8 qf0[4], qf1[4];
    {
        const float* qp0 = q + ((size_t)n0r*QH + (h << 4) + col)*D + (hi << 3);
        const float* qp1 = q + ((size_t)n1r*QH + (h << 4) + col)*D + (hi << 3);
        #pragma unroll
        for (int kc = 0; kc < 4; ++kc) {
            f32x4 a0 = *(const f32x4*)(qp0 + kc*32);
            f32x4 b0 = *(const f32x4*)(qp0 + kc*32 + 4);
            f32x4 a1 = *(const f32x4*)(qp1 + kc*32);
            f32x4 b1 = *(const f32x4*)(qp1 + kc*32 + 4);
            bf16x8 f0, f1;
            f0[0]=(short)f2bf(a0[0]*sm_scale); f0[1]=(short)f2bf(a0[1]*sm_scale);
            f0[2]=(short)f2bf(a0[2]*sm_scale); f0[3]=(short)f2bf(a0[3]*sm_scale);
            f0[4]=(short)f2bf(b0[0]*sm_scale); f0[5]=(short)f2bf(b0[1]*sm_scale);
            f0[6]=(short)f2bf(b0[2]*sm_scale); f0[7]=(short)f2bf(b0[3]*sm_scale);
            f1[0]=(short)f2bf(a1[0]*sm_scale); f1[1]=(short)f2bf(a1[1]*sm_scale);
            f1[2]=(short)f2bf(a1[2]*sm_scale); f1[3]=(short)f2bf(a1[3]*sm_scale);
            f1[4]=(short)f2bf(b1[0]*sm_scale); f1[5]=(short)f2bf(b1[1]*sm_scale);
            f1[6]=(short)f2bf(b1[2]*sm_scale); f1[7]=(short)f2bf(b1[3]*sm_scale);
            qf0[kc] = f0; qf1[kc] = f1;
        }
    }

    f32x4 oacc0[8], oacc1[8];
    #pragma unroll
    for (int dt = 0; dt < 8; ++dt) {
        oacc0[dt] = (f32x4){0.f,0.f,0.f,0.f};
        oacc1[dt] = (f32x4){0.f,0.f,0.f,0.f};
    }
    float rmax0 = -3e38f, rmax1 = -3e38f, rsum0 = 0.f, rsum1 = 0.f;

    const unsigned short* kvh = kvb + (size_t)h*HSTRIDE;

    auto STAGE = [&](int buf, int c) {
        const unsigned short* gp = kvh + ((size_t)(c*16 + (wid << 2))*64 + lane)*8;
        #pragma unroll
        for (int p = 0; p < 4; ++p)
            gload_lds16(gp + p*512, &lds[buf][(wid << 2) + p][lane][0]);
    };

    // softmax -> 4 packed bf16 words (B-frag of 16x16x32 PV)
    auto SMAX = [&](f32x4 sa, f32x4 sb, int lim, float& rm, float& rs,
                    f32x4* oaccr, unsigned int* pw) {
        float sv[8];
        if (lim < 32) {                      // boundary / inactive chunks
            const int mb = hi << 2;
            #pragma unroll
            for (int jj = 0; jj < 4; ++jj) {
                sv[jj]     = (mb + jj      < lim) ? sa[jj] : NEG_INF;
                sv[4 + jj] = (mb + jj + 16 < lim) ? sb[jj] : NEG_INF;
            }
        } else {
            #pragma unroll
            for (int jj = 0; jj < 4; ++jj) { sv[jj] = sa[jj]; sv[4 + jj] = sb[jj]; }
        }
        float pm = fmaxf(fmaxf(fmaxf(sv[0],sv[1]), fmaxf(sv[2],sv[3])),
                         fmaxf(fmaxf(sv[4],sv[5]), fmaxf(sv[6],sv[7])));
        if (!__all(pm <= rm + 8.0f)) {
            float tm = pm;
            tm = fmaxf(tm, __shfl_xor(tm, 16));
            tm = fmaxf(tm, __shfl_xor(tm, 32));
            float nm = fmaxf(rm, tm);
            float sc = __expf(rm - nm);
            rs *= sc;
            #pragma unroll
            for (int dt = 0; dt < 8; ++dt) {
                oaccr[dt][0] *= sc; oaccr[dt][1] *= sc;
                oaccr[dt][2] *= sc; oaccr[dt][3] *= sc;
            }
            rm = nm;
        }
        float p[8];
        #pragma unroll
        for (int i = 0; i < 8; ++i) p[i] = __expf(sv[i] - rm);
        rs += ((p[0]+p[1]) + (p[2]+p[3])) + ((p[4]+p[5]) + (p[6]+p[7]));
        asm("v_cvt_pk_bf16_f32 %0, %1, %2" : "=v"(pw[0]) : "v"(p[0]), "v"(p[1]));
        asm("v_cvt_pk_bf16_f32 %0, %1, %2" : "=v"(pw[1]) : "v"(p[2]), "v"(p[3]));
        asm("v_cvt_pk_bf16_f32 %0, %1, %2" : "=v"(pw[2]) : "v"(p[4]), "v"(p[5]));
        asm("v_cvt_pk_bf16_f32 %0, %1, %2" : "=v"(pw[3]) : "v"(p[6]), "v"(p[7]));
    };

    if (nchb > 0) {
        STAGE(0, 0);

        for (int c = 0; c < nchb; ++c) {
            // own chunk-c loads (issued one compute phase ago) complete
            asm volatile("s_waitcnt vmcnt(0)" ::: "memory");
            // publish chunk c; also orders iter c-1's reads of buf[(c+1)&1]
            __builtin_amdgcn_s_barrier();
            __builtin_amdgcn_sched_barrier(0);

            if (c + 1 < nchb) STAGE((c + 1) & 1, c + 1);

            const int m0 = c << 5;
            const unsigned short (*L)[64][8] = lds[c & 1];

            // ---- QK^T: 16 straight-line MFMAs, both rows ----
            f32x4 s10 = (f32x4){0,0,0,0}, s11 = (f32x4){0,0,0,0};
            f32x4 s00 = (f32x4){0,0,0,0}, s01 = (f32x4){0,0,0,0};
            __builtin_amdgcn_s_setprio(1);
            #pragma unroll
            for (int kc = 0; kc < 4; ++kc) {
                bf16x8 ca = *(const bf16x8*)&L[kc][lane][0];
                bf16x8 cb = *(const bf16x8*)&L[4 + kc][lane][0];
                s10 = __builtin_amdgcn_mfma_f32_16x16x32_bf16(ca, qf1[kc], s10, 0, 0, 0);
                s11 = __builtin_amdgcn_mfma_f32_16x16x32_bf16(cb, qf1[kc], s11, 0, 0, 0);
                s00 = __builtin_amdgcn_mfma_f32_16x16x32_bf16(ca, qf0[kc], s00, 0, 0, 0);
                s01 = __builtin_amdgcn_mfma_f32_16x16x32_bf16(cb, qf0[kc], s01, 0, 0, 0);
            }
            __builtin_amdgcn_s_setprio(0);

            unsigned int pw1[4], pw0[4];
            SMAX(s10, s11, mcnt1 - m0, rmax1, rsum1, oacc1, pw1);
            SMAX(s00, s01, mcnt0 - m0, rmax0, rsum0, oacc0, pw0);

            // ---- PV: one 16x16x32 MFMA per dt per row (in-place asm) ----
            {
                u32x4 b1v = {pw1[0], pw1[1], pw1[2], pw1[3]};
                u32x4 b0v = {pw0[0], pw0[1], pw0[2], pw0[3]};
                __builtin_amdgcn_s_setprio(1);
                #pragma unroll
                for (int dt = 0; dt < 8; ++dt) {
                    bf16x8 cv = *(const bf16x8*)&L[8 + dt][lane][0];
                    asm("v_mfma_f32_16x16x32_bf16 %0, %1, %2, %0"
                        : "+v"(oacc1[dt]) : "v"(cv), "v"(b1v));
                    asm("v_mfma_f32_16x16x32_bf16 %0, %1, %2, %0"
                        : "+v"(oacc0[dt]) : "v"(cv), "v"(b0v));
                }
                __builtin_amdgcn_s_setprio(0);
            }
        }
    }

    // ---- epilogue ----
    auto EPI = [&](int n, float rm, float rs, f32x4* oaccr, bool valid) {
        float r = rs;
        r += __shfl_xor(r, 16);
        r += __shfl_xor(r, 32);
        const float inv = valid ? (1.0f / r) : 0.0f;
        float* op = o + ((size_t)n*QH + (h << 4) + col)*D + (hi << 2);
        #pragma unroll
        for (int dt = 0; dt < 8; ++dt) {
            f32x4 w = oaccr[dt];
            w[0] *= inv; w[1] *= inv; w[2] *= inv; w[3] *= inv;
            *(f32x4*)(op + dt*16) = w;
        }
        if (lane < 16) {
            float lv = valid ? (rm + __logf(r)) : 0.0f;
            lse[((size_t)(h << 4) + col)*N_SEQ + n] = lv;
        }
    };
    EPI(n0r, rmax0, rsum0, oacc0, mcnt0 > 0);
    EPI(n1r, rmax1, rsum1, oacc1, mcnt1 > 0);
}

extern "C" void kernel_launch(void* const* d_in, const int* in_sizes, int n_in,
                              void* d_out, int out_size, void* d_ws, size_t ws_size,
                              hipStream_t stream)
{
    const float* q      = (const float*)d_in[0];
    const float* k      = (const float*)d_in[1];
    const float* v      = (const float*)d_in[2];
    const float* w_key  = (const float*)d_in[3];
    const float* pe_key = (const float*)d_in[4];
    const float* w_val  = (const float*)d_in[5];
    const float* pe_val = (const float*)d_in[6];

    float* o   = (float*)d_out;                    // (1, 8192, 32, 128)
    float* lse = o + (size_t)N_SEQ * QH * D;       // (1, 32, 8192)
    float* ck  = lse + (size_t)QH * N_SEQ;         // (1, 511, 2, 128)

    unsigned short* kvb = (unsigned short*)d_ws;   // [KH][NCH][16][64][8] bf16

    compress_kernel<<<dim3(MP), dim3(256), 0, stream>>>(
        k, v, w_key, pe_key, w_val, pe_val, ck, kvb);

    attn_kernel<<<dim3(N_SEQ/8, KH), dim3(256), 0, stream>>>(
        q, kvb, o, lse);
}